// Round 8
// baseline (15931.697 us; speedup 1.0000x reference)
//
#include <hip/hip_runtime.h>
#include <cstdint>
#include <cstddef>

// Problem constants
#define T_STEPS 8192
#define IN_DIM  1024
#define HID     1024
#define OUT_DIM 1024

// R16: un-confounded traffic-halving test. 128 blocks x 256 threads
// (4 waves, 1 wave/SIMD -- fixes R14's 2-waves/SIMD confound), 2 units
// per wave (8/block). Spin/deposit/barrier/hv BYTE-IDENTICAL to R12
// (11.62ms best). E/F/G widen to 2 units (+~180cy issue on-chain),
// traded against halved hot-line read pressure on the 16KB hbuf region
// (0.37 -> 0.19 line-reads/cy/line) which the R15 sleep-null says sets
// the ~3000cy store-visibility + poll-flight chain.
// History: R10 (early poll+stagger) -43%; R13 (masked retry) -50%;
// R14 (128x512, 2 waves/SIMD) -13%; R15 (s_sleep pre-spin) -29%, added
// its FULL duration => NO slack at the spin; only R9 (fusion) and
// R12 (prefetch double-buffer, drain removal) won. Spin inner structure
// (uniform loads, single drain, __all) is load-bearing -- never touch.
#define NBLK 128
#define TPB  256
#define UPB  8    // units per block
#define UPW  2    // units per wave

typedef __attribute__((ext_vector_type(4))) float f32x4;

#define PLOAD(p) __hip_atomic_load((p), __ATOMIC_RELAXED, __HIP_MEMORY_SCOPE_AGENT)

__device__ __forceinline__ float sigf(float x) {
  return 1.0f / (1.0f + __expf(-x));
}

template<int CTRL>
__device__ __forceinline__ float dpp_add(float v) {
  int p = __builtin_amdgcn_update_dpp(0, __float_as_int(v), CTRL, 0xf, 0xf, true);
  return v + __int_as_float(p);
}

// Full 64-lane sum, all-VALU (DPP). Result valid in LANE 63 only.
__device__ __forceinline__ float wave_sum63(float v) {
  v = dpp_add<0xB1>(v);    // quad_perm [1,0,3,2]
  v = dpp_add<0x4E>(v);    // quad_perm [2,3,0,1]
  v = dpp_add<0x141>(v);   // row_half_mirror
  v = dpp_add<0x140>(v);   // row_mirror
  v = dpp_add<0x142>(v);   // row_bcast15
  v = dpp_add<0x143>(v);   // row_bcast31
  return v;
}

// ---------------------------------------------------------------------------
// Fused persistent LSTM: tagged dataflow, hbuf: [2][1024] u64 {lo=tag,hi=h}.
// Iteration t (t = 0..T inclusive):
//   B) spin on my 256-chunk of slot t&1 for tag t (R12 shape, untouched)
//   C) deposit into lh[t&1]; raw barrier (lgkmcnt only; vmem in flight)
//   D) hv = full h_{t-1} from LDS
//   E) [t<T] gates for 2 units: chain init = pp[], 2x64 FMA vs reg-pinned
//      W_h, 8x DPP reduce -> lane 63: acts, c[q], h[q], publish 2 tags
//   -- sched_barrier: nothing below may delay the publish --
//   X) [t+2<T] x[t+2] prefetch into xnN (double-buffer: next spin's
//      vmcnt(0) drain is ~free -- R12's gain)
//   F) [t>0] y_{t-1} for 2 units (+DPP reduce), lane 63 stores out[t-1]
//   G) [t+1<T] pp[8] = partials of W_x . x_{t+1} from xnP (retired long ago)
//   R) xnP <= xnN (register rotate)
// Skew safety (block-count independent): a block publishes tag t+2 into
// slot s=t&1 only after its barrier C(t+1); passing poll t+1 requires every
// block published t+1, which required their barrier C(t) -- i.e. all
// consumers finished reading tag t from slot s. Depth-2 never skips a tag.
// ---------------------------------------------------------------------------
__global__ __launch_bounds__(TPB, 1) void lstm_fused(
    const float* __restrict__ Ww,                 // [4096, 2048]
    const float* __restrict__ xg,                 // [T, 1024]
    const float* __restrict__ owm,                // [1024, 1024]
    const float* __restrict__ wb,                 // [4096]
    const float* __restrict__ obv,                // [1024]
    unsigned long long* __restrict__ hbuf,        // [2][1024] tagged
    float* __restrict__ out)                      // [T, 1024]
{
  __shared__ float wxlds[32][HID];  // 128 KB: W_x rows m = ul*4+g, ul=0..7
  __shared__ float lh[2][HID];      // 8 KB: staged h, double-buffered

  const int tid = threadIdx.x;
  const int lane = tid & 63;
  const int wslot = tid >> 6;                    // 0..3
  const int u0 = blockIdx.x * UPB + wslot * UPW; // first unit of this wave

  // Stage W_x rows (32) for this block into LDS (float4, coalesced).
  {
    const float4* __restrict__ Ww4 = (const float4*)Ww;  // row stride 512 f4
    float4* wx4 = (float4*)&wxlds[0][0];
    for (int i = tid; i < 32 * 256; i += TPB) {
      const int m = i >> 8;            // 0..31
      const int e4 = i & 255;
      const int gg = m & 3;
      const int ul = m >> 2;
      const size_t row = (size_t)(gg * HID + blockIdx.x * UPB + ul) * 512;
      wx4[i] = Ww4[row + e4];                  // input half
    }
  }

  // W_h fragments: global -> registers directly (coalesced 16B/lane).
  // W[(q*4+r)*4+k]: unit q, gate-row r, chunk k.
  f32x4 W[32];
  {
    const f32x4* WwG = (const f32x4*)Ww;
#pragma unroll
    for (int q = 0; q < UPW; ++q)
#pragma unroll
      for (int r = 0; r < 4; ++r)
#pragma unroll
        for (int k = 0; k < 4; ++k)
          W[(q * 4 + r) * 4 + k] =
              WwG[(size_t)(r * HID + u0 + q) * 512 + 256 + k * 64 + lane];
#pragma unroll
    for (int i = 0; i < 16; ++i) asm volatile("" : "+v"(W[i]));
#pragma unroll
    for (int i = 16; i < 32; ++i) asm volatile("" : "+v"(W[i]));
  }

  // out_w rows for this wave's 2 units, pinned (32 VGPRs).
  f32x4 O[8];
  {
#pragma unroll
    for (int q = 0; q < UPW; ++q) {
      const f32x4* ow4 = (const f32x4*)(owm + (size_t)(u0 + q) * HID);
#pragma unroll
      for (int k = 0; k < 4; ++k) O[q * 4 + k] = ow4[k * 64 + lane];
    }
#pragma unroll
    for (int i = 0; i < 8; ++i) asm volatile("" : "+v"(O[i]));
  }

  float bi[UPW], bf[UPW], bg[UPW], bo[UPW], oby[UPW];
#pragma unroll
  for (int q = 0; q < UPW; ++q) {
    bi[q] = wb[u0 + q];           bf[q] = wb[HID + u0 + q];
    bg[q] = wb[2 * HID + u0 + q]; bo[q] = wb[3 * HID + u0 + q];
    oby[q] = obv[u0 + q];
  }

  __syncthreads();   // wxlds ready

  // Prologue: x-partials for step 0, and xnP = x[1] for step 0's G.
  float pp[8];
  {
    const f32x4* xt4 = (const f32x4*)xg;
    f32x4 x0[4];
#pragma unroll
    for (int k = 0; k < 4; ++k) x0[k] = xt4[k * 64 + lane];
#pragma unroll
    for (int q = 0; q < UPW; ++q) {
      const f32x4* wxl = (const f32x4*)&wxlds[(wslot * UPW + q) * 4][0];
#pragma unroll
      for (int r = 0; r < 4; ++r) {
        float s = 0.0f;
#pragma unroll
        for (int k = 0; k < 4; ++k) {
          const f32x4 wx = wxl[r * 256 + k * 64 + lane];
          s = fmaf(wx.x, x0[k].x, s); s = fmaf(wx.y, x0[k].y, s);
          s = fmaf(wx.z, x0[k].z, s); s = fmaf(wx.w, x0[k].w, s);
        }
        pp[q * 4 + r] = s;
      }
    }
  }
  f32x4 xnP[4];
  {
    const f32x4* xt4 = (const f32x4*)(xg + (size_t)1 * IN_DIM);
#pragma unroll
    for (int k = 0; k < 4; ++k) xnP[k] = xt4[k * 64 + lane];
  }

  float cs[UPW];
#pragma unroll
  for (int q = 0; q < UPW; ++q) cs[q] = 0.0f;

  for (int t = 0; t <= T_STEPS; ++t) {
    // B) spin: first vmem ops of the iteration (R12 single-set form).
    const unsigned long long* hs = hbuf + (size_t)(t & 1) * HID + wslot * 256;
    const unsigned want = (unsigned)t;
    unsigned long long p0, p1, p2, p3;
    for (;;) {
      p0 = PLOAD(hs + lane);
      p1 = PLOAD(hs + 64 + lane);
      p2 = PLOAD(hs + 128 + lane);
      p3 = PLOAD(hs + 192 + lane);
      bool ok = ((unsigned)p0 == want) & ((unsigned)p1 == want) &
                ((unsigned)p2 == want) & ((unsigned)p3 == want);
      if (__all((int)ok)) break;
    }
    {
      float* dst = &lh[t & 1][wslot * 256];
      dst[lane]       = __uint_as_float((unsigned)(p0 >> 32));
      dst[64 + lane]  = __uint_as_float((unsigned)(p1 >> 32));
      dst[128 + lane] = __uint_as_float((unsigned)(p2 >> 32));
      dst[192 + lane] = __uint_as_float((unsigned)(p3 >> 32));
    }

    // C) raw barrier: drain LDS ops only; global loads/stores stay in flight
    asm volatile("s_waitcnt lgkmcnt(0)\n\ts_barrier" ::: "memory");

    // D) full h_{t-1} from LDS
    const f32x4* lhp = (const f32x4*)&lh[t & 1][0];
    f32x4 hv[4];
#pragma unroll
    for (int k = 0; k < 4; ++k) hv[k] = lhp[k * 64 + lane];

    // E) gates -> h_t -> publish (critical path; lane 63 is the publisher)
    if (t < T_STEPS) {
      float a[8];
#pragma unroll
      for (int q = 0; q < UPW; ++q)
#pragma unroll
        for (int r = 0; r < 4; ++r) {
          float s = pp[q * 4 + r];
          const int w0 = (q * 4 + r) * 4;
#pragma unroll
          for (int k = 0; k < 4; ++k) {
            s = fmaf(W[w0+k].x, hv[k].x, s); s = fmaf(W[w0+k].y, hv[k].y, s);
            s = fmaf(W[w0+k].z, hv[k].z, s); s = fmaf(W[w0+k].w, hv[k].w, s);
          }
          a[q * 4 + r] = wave_sum63(s);
        }
#pragma unroll
      for (int q = 0; q < UPW; ++q) {
        const float gi = a[q*4+0] + bi[q], gf = a[q*4+1] + bf[q];
        const float gc = a[q*4+2] + bg[q], go = a[q*4+3] + bo[q];
        const float si = sigf(gi), sf = sigf(gf), so = sigf(go);
        const float tg = fmaf(2.0f, sigf(2.0f * gc), -1.0f);   // tanh
        cs[q] = fmaf(sf, cs[q], si * tg);
        const float h = so * fmaf(2.0f, sigf(2.0f * cs[q]), -1.0f);
        if (lane == 63) {
          const unsigned long long pk =
              ((unsigned long long)__float_as_uint(h) << 32) | (unsigned)(t + 1);
          __hip_atomic_store(hbuf + (size_t)((t + 1) & 1) * HID + u0 + q, pk,
                             __ATOMIC_RELAXED, __HIP_MEMORY_SCOPE_AGENT);
        }
      }
    }

    // Nothing below may be scheduled above the publish.
    __builtin_amdgcn_sched_barrier(0);

    // X) x[t+2] prefetch: earliest vmem point after publish; retires during
    // the next spin, so its drain is ~free (R12's gain, kept).
    f32x4 xnN[4];
    const bool pf = (t + 2 < T_STEPS);
    if (pf) {
      const f32x4* xt4 = (const f32x4*)(xg + (size_t)(t + 2) * IN_DIM);
#pragma unroll
      for (int k = 0; k < 4; ++k) xnN[k] = xt4[k * 64 + lane];
    }

    // F) y_{t-1} for both units (shadow work)
    if (t > 0) {
#pragma unroll
      for (int q = 0; q < UPW; ++q) {
        float yv = 0.0f;
#pragma unroll
        for (int k = 0; k < 4; ++k) {
          yv = fmaf(O[q*4+k].x, hv[k].x, yv); yv = fmaf(O[q*4+k].y, hv[k].y, yv);
          yv = fmaf(O[q*4+k].z, hv[k].z, yv); yv = fmaf(O[q*4+k].w, hv[k].w, yv);
        }
        yv = wave_sum63(yv);
        if (lane == 63) out[(size_t)(t - 1) * OUT_DIM + u0 + q] = yv + oby[q];
      }
    }
    __builtin_amdgcn_sched_barrier(0);

    // G) x-partials for step t+1 from xnP (issued a full step ago).
    if (t + 1 < T_STEPS) {
#pragma unroll
      for (int q = 0; q < UPW; ++q) {
        const f32x4* wxl = (const f32x4*)&wxlds[(wslot * UPW + q) * 4][0];
#pragma unroll
        for (int r = 0; r < 4; ++r) {
          float s = 0.0f;
#pragma unroll
          for (int k = 0; k < 4; ++k) {
            const f32x4 wx = wxl[r * 256 + k * 64 + lane];
            s = fmaf(wx.x, xnP[k].x, s); s = fmaf(wx.y, xnP[k].y, s);
            s = fmaf(wx.z, xnP[k].z, s); s = fmaf(wx.w, xnP[k].w, s);
          }
          pp[q * 4 + r] = s;
        }
      }
    }

    // R) rotate the x double-buffer (16 v_mov in the shadow).
    if (pf) {
#pragma unroll
      for (int k = 0; k < 4; ++k) xnP[k] = xnN[k];
    }
  }
}

// ---------------------------------------------------------------------------
// Workspace layout (bytes): [0, 16K) : hbuf[2][1024] tagged u64 (memset 0)
// ---------------------------------------------------------------------------
extern "C" void kernel_launch(void* const* d_in, const int* in_sizes, int n_in,
                              void* d_out, int out_size, void* d_ws, size_t ws_size,
                              hipStream_t stream) {
  (void)in_sizes; (void)n_in; (void)out_size; (void)ws_size;

  const float* x     = (const float*)d_in[0];  // [T,1,IN]
  const float* W_w   = (const float*)d_in[1];  // [4096, 2048]
  const float* W_b   = (const float*)d_in[2];  // [4096]
  const float* out_w = (const float*)d_in[3];  // [1024, 1024]
  const float* out_b = (const float*)d_in[4];  // [1024]
  float* out = (float*)d_out;                  // [T,1,1024]

  unsigned long long* hbuf = (unsigned long long*)d_ws;
  hipMemsetAsync(d_ws, 0, 16384, stream);

  lstm_fused<<<NBLK, TPB, 0, stream>>>(W_w, x, out_w, W_b, out_b, hbuf, out);
}